// Round 7
// baseline (1095.069 us; speedup 1.0000x reference)
//
#include <hip/hip_runtime.h>
#include <stdint.h>

typedef float f32x4 __attribute__((ext_vector_type(4)));
typedef short s16x8 __attribute__((ext_vector_type(8)));
typedef short s16x4 __attribute__((ext_vector_type(4)));
typedef uint32_t u32x4 __attribute__((ext_vector_type(4)));

#define HDIM 128
#define TLEN 512
#define BT 16

__device__ __forceinline__ unsigned short f2bf(float f) {
    union { float f; uint32_t u; } v; v.f = f;
    uint32_t r = v.u + 0x7FFFu + ((v.u >> 16) & 1u);
    return (unsigned short)(r >> 16);
}
__device__ __forceinline__ float bfhi(uint32_t u){ union{uint32_t u;float f;}v; v.u = u & 0xFFFF0000u; return v.f; }
__device__ __forceinline__ float bflo(uint32_t u){ union{uint32_t u;float f;}v; v.u = u << 16; return v.f; }
__device__ __forceinline__ float bf2f(short s){ union{uint32_t u;float f;}v; v.u = ((uint32_t)(unsigned short)s) << 16; return v.f; }

__device__ __forceinline__ float sigmoidf_(float x){
    float e = __expf(-x);
    return __builtin_amdgcn_rcpf(1.0f + e);
}
__device__ __forceinline__ float tanhf_(float x){
    float e = __expf(2.0f * x);
    return 1.0f - 2.0f * __builtin_amdgcn_rcpf(1.0f + e);
}

#define MFMA16(A, B, C) __builtin_amdgcn_mfma_f32_16x16x32_bf16((A), (B), (C), 0, 0, 0)

__global__ __launch_bounds__(512, 2) void lstm_fused_kernel(
    const float* __restrict__ x,      // (2048,512,1)
    const float* __restrict__ Wih0,   // (512,1)
    const float* __restrict__ Whh0,   // (512,128)
    const float* __restrict__ bih0,
    const float* __restrict__ bhh0,
    const float* __restrict__ Wih1,   // (512,128)
    const float* __restrict__ Whh1,   // (512,128)
    const float* __restrict__ bih1,
    const float* __restrict__ bhh1,
    const float* __restrict__ W1,     // (64,128)
    const float* __restrict__ b1,     // (64)
    const float* __restrict__ W2,     // (8,64)
    const float* __restrict__ b2,     // (8)
    float* __restrict__ out)          // (2048,8)
{
    // Whh1 fragment-ordered in LDS (128 KB); h0 ring (depth 4); h1 ping-pong;
    // b1 broadcast; 2 sync counters. Head scratch aliases h0ring/h1f (NOT wh1lds,
    // which the L1 epilogue still reads).
    __shared__ __align__(16) short wh1lds[65536];        // 128 KB
    __shared__ __align__(16) short h0ring[4][2048];      // 16 KB
    __shared__ __align__(16) short h1f[2][2048];         // 8 KB
    __shared__ __align__(16) float b1lds[4][8][16];      // 2 KB
    __shared__ int syncc[2];                             // [0]=c0 (L0), [1]=c1 (L1)

    const int tid = threadIdx.x;
    const int w   = tid >> 6;
    const int wl  = w & 3;          // wave index within team
    const bool isL0 = (w < 4);      // waves 0-3: layer 0 ; waves 4-7: layer 1
    const int l = tid & 63;
    const int n = l & 15;           // batch col
    const int q = l >> 4;           // k-group / row-quad
    const int b0 = blockIdx.x * BT;
    const float* xrow = x + (size_t)(b0 + n) * TLEN;

    if (tid == 0) { syncc[0] = 0; syncc[1] = 0; }

    // ---- stage Whh1 into LDS, fragment-ordered per L1 wave (all 512 threads) ----
    for (int s2 = tid; s2 < 8192; s2 += 512) {
        const int ll = s2 & 63, t2 = (s2 >> 6) & 7, cc = (s2 >> 9) & 3, wv = s2 >> 11;
        const int row = (t2 >> 1) * 128 + 32 * wv + 16 * (t2 & 1) + (ll & 15);
        const int k0  = cc * 32 + (ll >> 4) * 8;
        const float* p = Whh1 + row * HDIM + k0;
        s16x8 a;
        #pragma unroll
        for (int j = 0; j < 8; ++j) a[j] = (short)f2bf(p[j]);
        *(s16x8*)&wh1lds[s2 * 8] = a;
    }
    // ---- b1 broadcast table ----
    {
        const int idx = tid;
        const int wv = idx >> 7, t2 = (idx >> 4) & 7, j = idx & 15;
        const int row = (t2 >> 1) * 128 + 32 * wv + 16 * (t2 & 1) + j;
        b1lds[wv][t2][j] = bih1[row] + bhh1[row];
    }
    // zero h1[-1]  (read slot = (0-1)&1 = 1)
    for (int s2 = tid; s2 < 1024; s2 += 512) ((uint32_t*)h1f[1])[s2] = 0u;

    // B-fragment write slots for this lane's unit quads (h=0 / h=1)
    const int ub0 = 32 * wl + 4 * q;
    const int ub1 = ub0 + 16;
    const int fo0 = ((ub0 >> 5) * 64 + n + 16 * ((ub0 >> 3) & 3)) * 8 + (ub0 & 7);
    const int fo1 = ((ub1 >> 5) * 64 + n + 16 * ((ub1 >> 3) & 3)) * 8 + (ub1 & 7);

// all-lane broadcast poll (uniform branch), then acquire
#define WAITGE(T0, T1) do {                                                   \
    volatile const int* f0_ = &syncc[0];                                      \
    volatile const int* f1_ = &syncc[1];                                      \
    while (*f0_ < (T0) || *f1_ < (T1)) __builtin_amdgcn_s_sleep(1);           \
    __threadfence_block();                                                    \
} while (0)

// release + post one completion for team TM
#define POST(TM) do {                                                         \
    __threadfence_block();                                                    \
    if (l == 0) atomicAdd(&syncc[TM], 1);                                     \
} while (0)

    if (isL0) {
        // ---- L0 team: Whh0 fully in registers ----
        s16x8 w0f[4][8];
        #pragma unroll
        for (int c = 0; c < 4; ++c) {
            #pragma unroll
            for (int t2 = 0; t2 < 8; ++t2) {
                const int row = (t2 >> 1) * 128 + 32 * wl + 16 * (t2 & 1) + n;
                const int k0 = c * 32 + q * 8;
                const float* p = Whh0 + row * HDIM + k0;
                s16x8 a;
                #pragma unroll
                for (int j = 0; j < 8; ++j) a[j] = (short)f2bf(p[j]);
                w0f[c][t2] = a;
            }
        }
        // packed (bias0, wx) per owned gate-row
        u32x4 bwx[8];
        #pragma unroll
        for (int t2 = 0; t2 < 8; ++t2) {
            #pragma unroll
            for (int r = 0; r < 4; ++r) {
                const int row = (t2 >> 1) * 128 + 32 * wl + 16 * (t2 & 1) + 4 * q + r;
                bwx[t2][r] = ((uint32_t)f2bf(Wih0[row]) << 16) | f2bf(bih0[row] + bhh0[row]);
            }
        }
        float c0_[2][4] = {{0.f,0.f,0.f,0.f},{0.f,0.f,0.f,0.f}};

        // prologue: h0[0] = pointwise(b0 + wx*x[0]) -> h0ring[0]
        {
            const float x0 = xrow[0];
            #pragma unroll
            for (int h = 0; h < 2; ++h) {
                s16x4 hw;
                #pragma unroll
                for (int r = 0; r < 4; ++r) {
                    const float pi = fmaf(bfhi(bwx[0 + h][r]), x0, bflo(bwx[0 + h][r]));
                    const float pg = fmaf(bfhi(bwx[4 + h][r]), x0, bflo(bwx[4 + h][r]));
                    const float po = fmaf(bfhi(bwx[6 + h][r]), x0, bflo(bwx[6 + h][r]));
                    const float ig = sigmoidf_(pi);
                    const float gg = tanhf_(pg);
                    const float og = sigmoidf_(po);
                    const float cc = ig * gg;          // f * c(-1) = 0
                    c0_[h][r] = cc;
                    hw[r] = (short)f2bf(og * tanhf_(cc));
                }
                *(s16x4*)&h0ring[0][h ? fo1 : fo0] = hw;
            }
        }
        __syncthreads();   // staging + prologue + flag-init visible to all

        // L0 iter i: consumes h0[i] (slot i&3), produces h0[i+1] (slot (i+1)&3).
        // Waits: own team done iter i-1 (h0[i] complete): c0 >= 4i;
        //        ring WAR (slot holds h0[i-3]; L1 read it at iter i-3): c1 >= 4(i-2).
        #pragma unroll 1
        for (int i = 0; i < 511; ++i) {
            WAITGE(4 * i, 4 * (i - 2));
            const short* R0 = h0ring[i & 3];
            short*       W0 = h0ring[(i + 1) & 3];
            const float xv_ = xrow[i + 1];
            s16x8 hb_[4];
            #pragma unroll
            for (int c = 0; c < 4; ++c) hb_[c] = *(const s16x8*)&R0[(c * 64 + l) * 8];
            f32x4 a_[8];
            #pragma unroll
            for (int t2 = 0; t2 < 8; ++t2) {
                #pragma unroll
                for (int r = 0; r < 4; ++r)
                    a_[t2][r] = fmaf(bfhi(bwx[t2][r]), xv_, bflo(bwx[t2][r]));
            }
            #pragma unroll
            for (int c = 0; c < 4; ++c) {
                #pragma unroll
                for (int t2 = 0; t2 < 8; ++t2)
                    a_[t2] = MFMA16(w0f[c][t2], hb_[c], a_[t2]);
            }
            #pragma unroll
            for (int h = 0; h < 2; ++h) {
                s16x4 hw;
                #pragma unroll
                for (int r = 0; r < 4; ++r) {
                    const float ig = sigmoidf_(a_[0 + h][r]);
                    const float fg = sigmoidf_(a_[2 + h][r]);
                    const float gg = tanhf_(a_[4 + h][r]);
                    const float og = sigmoidf_(a_[6 + h][r]);
                    const float cc = fmaf(fg, c0_[h][r], ig * gg);
                    c0_[h][r] = cc;
                    hw[r] = (short)f2bf(og * tanhf_(cc));
                }
                *(s16x4*)&W0[h ? fo1 : fo0] = hw;
            }
            POST(0);
        }
    } else {
        // ---- L1 team: Wih1 in registers, Whh1 streamed from LDS ----
        s16x8 wi1f[4][8];
        #pragma unroll
        for (int c = 0; c < 4; ++c) {
            #pragma unroll
            for (int t2 = 0; t2 < 8; ++t2) {
                const int row = (t2 >> 1) * 128 + 32 * wl + 16 * (t2 & 1) + n;
                const int k0 = c * 32 + q * 8;
                const float* p = Wih1 + row * HDIM + k0;
                s16x8 a;
                #pragma unroll
                for (int j = 0; j < 8; ++j) a[j] = (short)f2bf(p[j]);
                wi1f[c][t2] = a;
            }
        }
        float c1_[2][4] = {{0.f,0.f,0.f,0.f},{0.f,0.f,0.f,0.f}};

        __syncthreads();   // staging + prologue + flag-init visible to all

        // L1 iter k: consumes h0[k] (slot k&3) and h1[k-1] (slot (k+1)&1),
        // produces h1[k] (slot k&1).
        // Waits: h0[k] ready (L0 done iter k-1): c0 >= 4k;
        //        team done iter k-1 (h1[k-1] complete + write slot free): c1 >= 4k.
        #pragma unroll 1
        for (int k = 0; k < 511; ++k) {
            WAITGE(4 * k, 4 * k);
            const short* R0 = h0ring[k & 3];
            const short* R1 = h1f[(k + 1) & 1];
            short*       W1B = h1f[k & 1];
            s16x8 hb0_[4], hb1_[4];
            #pragma unroll
            for (int c = 0; c < 4; ++c) {
                hb0_[c] = *(const s16x8*)&R0[(c * 64 + l) * 8];
                hb1_[c] = *(const s16x8*)&R1[(c * 64 + l) * 8];
            }
            f32x4 a_[8];
            #pragma unroll
            for (int t2 = 0; t2 < 8; ++t2)
                a_[t2] = *(const f32x4*)&b1lds[wl][t2][q * 4];
            #pragma unroll
            for (int c = 0; c < 4; ++c) {
                #pragma unroll
                for (int t2 = 0; t2 < 8; ++t2)
                    a_[t2] = MFMA16(wi1f[c][t2], hb0_[c], a_[t2]);
            }
            #pragma unroll
            for (int c = 0; c < 4; ++c) {
                s16x8 wt_[8];
                #pragma unroll
                for (int t2 = 0; t2 < 8; ++t2)
                    wt_[t2] = *(const s16x8*)&wh1lds[(((wl * 4 + c) * 8 + t2) * 64 + l) * 8];
                #pragma unroll
                for (int t2 = 0; t2 < 8; ++t2)
                    a_[t2] = MFMA16(wt_[t2], hb1_[c], a_[t2]);
            }
            #pragma unroll
            for (int h = 0; h < 2; ++h) {
                s16x4 hw;
                #pragma unroll
                for (int r = 0; r < 4; ++r) {
                    const float ig = sigmoidf_(a_[0 + h][r]);
                    const float fg = sigmoidf_(a_[2 + h][r]);
                    const float gg = tanhf_(a_[4 + h][r]);
                    const float og = sigmoidf_(a_[6 + h][r]);
                    const float cc = fmaf(fg, c1_[h][r], ig * gg);
                    c1_[h][r] = cc;
                    hw[r] = (short)f2bf(og * tanhf_(cc));
                }
                *(s16x4*)&W1B[h ? fo1 : fo0] = hw;
            }
            POST(1);
        }

        // ---- epilogue t=511: gates1 only; final h1 -> headH (f32) ----
        WAITGE(4 * 511, 4 * 511);
        {
            const short* R0 = h0ring[511 & 3];   // h0[511]
            const short* R1 = h1f[0];            // h1[510]
            s16x8 hb0_[4], hb1_[4];
            #pragma unroll
            for (int c = 0; c < 4; ++c) {
                hb0_[c] = *(const s16x8*)&R0[(c * 64 + l) * 8];
                hb1_[c] = *(const s16x8*)&R1[(c * 64 + l) * 8];
            }
            f32x4 a_[8];
            #pragma unroll
            for (int t2 = 0; t2 < 8; ++t2)
                a_[t2] = *(const f32x4*)&b1lds[wl][t2][q * 4];
            #pragma unroll
            for (int c = 0; c < 4; ++c) {
                s16x8 wt_[8];
                #pragma unroll
                for (int t2 = 0; t2 < 8; ++t2)
                    wt_[t2] = *(const s16x8*)&wh1lds[(((wl * 4 + c) * 8 + t2) * 64 + l) * 8];
                #pragma unroll
                for (int t2 = 0; t2 < 8; ++t2) {
                    a_[t2] = MFMA16(wi1f[c][t2], hb0_[c], a_[t2]);
                    a_[t2] = MFMA16(wt_[t2], hb1_[c], a_[t2]);
                }
            }
            // headH aliases h0ring slots 0-1 (dead; epilogue reads slot 3 only)
            float* headH = (float*)&h0ring[0][0];
            #pragma unroll
            for (int h = 0; h < 2; ++h) {
                f32x4 hv;
                #pragma unroll
                for (int r = 0; r < 4; ++r) {
                    const float ig = sigmoidf_(a_[0 + h][r]);
                    const float fg = sigmoidf_(a_[2 + h][r]);
                    const float gg = tanhf_(a_[4 + h][r]);
                    const float og = sigmoidf_(a_[6 + h][r]);
                    const float cc = fmaf(fg, c1_[h][r], ig * gg);
                    hv[r] = og * tanhf_(cc);
                }
                *(f32x4*)&headH[n * HDIM + (h ? ub1 : ub0)] = hv;
            }
        }
    }

    __syncthreads();

    // ---- head: hidden = relu(h @ W1^T + b1) ; logits = hidden @ W2^T + b2 ----
    float* headH = (float*)&h0ring[0][0];   // [16][128] (8 KB = ring slots 0-1)
    float* headL = (float*)&h1f[0][0];      // [16][64]  (4 KB = h1f[0])

    #pragma unroll
    for (int rep = 0; rep < 2; ++rep) {
        const int idx = tid + rep * 512;     // 1024 = 16 batch * 64 hidden
        const int nn = idx >> 6, j = idx & 63;
        float s = b1[j];
        const float* wrow = W1 + j * HDIM;
        const float* hrow = headH + nn * HDIM;
        #pragma unroll
        for (int k = 0; k < HDIM; k += 4) {
            const f32x4 hv = *(const f32x4*)&hrow[k];
            const f32x4 wv = *(const f32x4*)&wrow[k];
            s += hv[0]*wv[0] + hv[1]*wv[1] + hv[2]*wv[2] + hv[3]*wv[3];
        }
        headL[nn * 64 + j] = fmaxf(s, 0.0f);
    }
    __syncthreads();

    if (tid < 128) {
        const int nn = tid >> 3, cls = tid & 7;
        float s = b2[cls];
        const float* wrow = W2 + cls * 64;
        const float* hrow = headL + nn * 64;
        #pragma unroll
        for (int k = 0; k < 64; k += 4) {
            const f32x4 hv = *(const f32x4*)&hrow[k];
            const f32x4 wv = *(const f32x4*)&wrow[k];
            s += hv[0]*wv[0] + hv[1]*wv[1] + hv[2]*wv[2] + hv[3]*wv[3];
        }
        out[(size_t)(b0 + nn) * 8 + cls] = s;
    }
}

extern "C" void kernel_launch(void* const* d_in, const int* in_sizes, int n_in,
                              void* d_out, int out_size, void* d_ws, size_t ws_size,
                              hipStream_t stream) {
    const float* x    = (const float*)d_in[0];
    const float* Wih0 = (const float*)d_in[1];
    const float* Whh0 = (const float*)d_in[2];
    const float* bih0 = (const float*)d_in[3];
    const float* bhh0 = (const float*)d_in[4];
    const float* Wih1 = (const float*)d_in[5];
    const float* Whh1 = (const float*)d_in[6];
    const float* bih1 = (const float*)d_in[7];
    const float* bhh1 = (const float*)d_in[8];
    const float* W1   = (const float*)d_in[9];
    const float* b1   = (const float*)d_in[10];
    const float* W2   = (const float*)d_in[11];
    const float* b2   = (const float*)d_in[12];
    float* outp = (float*)d_out;

    lstm_fused_kernel<<<128, 512, 0, stream>>>(
        x, Wih0, Whh0, bih0, bhh0, Wih1, Whh1, bih1, bhh1, W1, b1, W2, b2, outp);
}

// Round 8
// 954.753 us; speedup vs baseline: 1.1470x; 1.1470x over previous
//
#include <hip/hip_runtime.h>
#include <stdint.h>

typedef float f32x4 __attribute__((ext_vector_type(4)));
typedef short s16x8 __attribute__((ext_vector_type(8)));
typedef short s16x4 __attribute__((ext_vector_type(4)));
typedef uint32_t u32x4 __attribute__((ext_vector_type(4)));

#define HDIM 128
#define TLEN 512
#define BT 16

__device__ __forceinline__ unsigned short f2bf(float f) {
    union { float f; uint32_t u; } v; v.f = f;
    uint32_t r = v.u + 0x7FFFu + ((v.u >> 16) & 1u);
    return (unsigned short)(r >> 16);
}
__device__ __forceinline__ float bfhi(uint32_t u){ union{uint32_t u;float f;}v; v.u = u & 0xFFFF0000u; return v.f; }
__device__ __forceinline__ float bflo(uint32_t u){ union{uint32_t u;float f;}v; v.u = u << 16; return v.f; }
__device__ __forceinline__ float bf2f(short s){ union{uint32_t u;float f;}v; v.u = ((uint32_t)(unsigned short)s) << 16; return v.f; }

__device__ __forceinline__ float sigmoidf_(float x){
    float e = __expf(-x);
    return __builtin_amdgcn_rcpf(1.0f + e);
}
__device__ __forceinline__ float tanhf_(float x){
    float e = __expf(2.0f * x);
    return 1.0f - 2.0f * __builtin_amdgcn_rcpf(1.0f + e);
}

#define MFMA16(A, B, C) __builtin_amdgcn_mfma_f32_16x16x32_bf16((A), (B), (C), 0, 0, 0)
#define UNPK(arr, idx) (((idx) & 1) ? bfhi(arr[(idx) >> 1]) : bflo(arr[(idx) >> 1]))

// ============================================================================
// Pipelined 2-block-per-pair kernel: even blocks = layer 0 (producer),
// odd blocks = layer 1 + head (consumer). h0 stream via full-length global
// ring (no backpressure -> deadlock-free under any scheduling).
// ============================================================================
__global__ __launch_bounds__(512, 2) void lstm_pipe_kernel(
    const float* __restrict__ x,
    const float* __restrict__ Wih0,
    const float* __restrict__ Whh0,
    const float* __restrict__ bih0,
    const float* __restrict__ bhh0,
    const float* __restrict__ Wih1,
    const float* __restrict__ Whh1,
    const float* __restrict__ bih1,
    const float* __restrict__ bhh1,
    const float* __restrict__ W1,
    const float* __restrict__ b1,
    const float* __restrict__ W2,
    const float* __restrict__ b2,
    short* __restrict__ ring,        // [128 pairs][512 t][2048 shorts]
    int* __restrict__ flags,         // [128] chunks-complete counters
    float* __restrict__ out)
{
    __shared__ __align__(16) short h0A[2][2048];       // A: h0 ping-pong frags
    __shared__ __align__(16) short h1f[2][2048];       // B: h1 ping-pong frags
    __shared__ __align__(16) float headH[16 * HDIM];   // B: final h1 f32
    __shared__ __align__(16) float headL[16 * 64];     // B: relu layer

    const int role = blockIdx.x & 1;     // 0 = layer0, 1 = layer1+head
    const int p    = blockIdx.x >> 1;    // pair index = batch group
    const int tid  = threadIdx.x;
    const int w = tid >> 6;              // wave 0..7, owns units [16w,16w+16)
    const int l = tid & 63;
    const int n = l & 15;                // batch col
    const int q = l >> 4;                // k-group / row-quad
    const int b0 = p * BT;
    const float* xrow = x + (size_t)(b0 + n) * TLEN;
    short* ringp = ring + (size_t)p * TLEN * 2048;

    // B-fragment slot for this lane's 4 units
    const int u0 = w * 16 + q * 4;
    const int fragoff = (((u0 >> 5) * 64) + n + 16 * ((u0 >> 3) & 3)) * 8 + (u0 & 7);

    if (role == 0) {
        // ================= A: layer 0 producer =================
        // Whh0 fragments in registers: 16 x s16x8 = 64 VGPRs
        s16x8 w0f[4][4];
        #pragma unroll
        for (int c = 0; c < 4; ++c) {
            #pragma unroll
            for (int tile = 0; tile < 4; ++tile) {
                const int g  = tile * 128 + w * 16 + n;
                const int k0 = c * 32 + q * 8;
                const float* pw = Whh0 + g * HDIM + k0;
                s16x8 a;
                #pragma unroll
                for (int j = 0; j < 8; ++j) a[j] = (short)f2bf(pw[j]);
                w0f[c][tile] = a;
            }
        }
        uint32_t b0p[8], wxp[8];
        #pragma unroll
        for (int i = 0; i < 8; ++i) {
            const int tr0 = 2 * i;
            const int tile = tr0 >> 2, r0 = tr0 & 3;
            const int g0 = tile * 128 + u0 + r0;
            const int g1 = g0 + 1;
            b0p[i] = ((uint32_t)f2bf(bih0[g1] + bhh0[g1]) << 16) | f2bf(bih0[g0] + bhh0[g0]);
            wxp[i] = ((uint32_t)f2bf(Wih0[g1]) << 16) | f2bf(Wih0[g0]);
        }
        float c0v[4] = {0.f, 0.f, 0.f, 0.f};

        // prologue: h0[0] = pointwise(b0 + wx*x[0])
        {
            const float x0 = xrow[0];
            s16x4 hw;
            #pragma unroll
            for (int r = 0; r < 4; ++r) {
                const float pi = fmaf(UNPK(wxp, r),      x0, UNPK(b0p, r));
                const float pg = fmaf(UNPK(wxp, 8 + r),  x0, UNPK(b0p, 8 + r));
                const float po = fmaf(UNPK(wxp, 12 + r), x0, UNPK(b0p, 12 + r));
                const float ig = sigmoidf_(pi);
                const float gg = tanhf_(pg);
                const float og = sigmoidf_(po);
                const float cc = ig * gg;           // f*c(-1) = 0
                c0v[r] = cc;
                hw[r] = (short)f2bf(og * tanhf_(cc));
            }
            *(s16x4*)&h0A[0][fragoff] = hw;
            *(s16x4*)&ringp[fragoff] = hw;          // ring slot t=0
        }
        __syncthreads();

        #pragma unroll 1
        for (int i = 0; i < 511; ++i) {
            const short* R = h0A[i & 1];
            short*       W = h0A[(i + 1) & 1];
            const float xv = xrow[i + 1];
            s16x8 hb[4];
            #pragma unroll
            for (int c = 0; c < 4; ++c) hb[c] = *(const s16x8*)&R[(c * 64 + l) * 8];
            f32x4 a[4];
            #pragma unroll
            for (int tile = 0; tile < 4; ++tile) {
                #pragma unroll
                for (int r = 0; r < 4; ++r) {
                    const int tr = tile * 4 + r;
                    a[tile][r] = fmaf(UNPK(wxp, tr), xv, UNPK(b0p, tr));
                }
            }
            #pragma unroll
            for (int c = 0; c < 4; ++c) {
                #pragma unroll
                for (int tile = 0; tile < 4; ++tile)
                    a[tile] = MFMA16(w0f[c][tile], hb[c], a[tile]);
            }
            s16x4 hw;
            #pragma unroll
            for (int r = 0; r < 4; ++r) {
                const float ig = sigmoidf_(a[0][r]);
                const float fg = sigmoidf_(a[1][r]);
                const float gg = tanhf_(a[2][r]);
                const float og = sigmoidf_(a[3][r]);
                const float cc = fmaf(fg, c0v[r], ig * gg);
                c0v[r] = cc;
                hw[r] = (short)f2bf(og * tanhf_(cc));
            }
            *(s16x4*)&W[fragoff] = hw;
            *(s16x4*)&ringp[(size_t)(i + 1) * 2048 + fragoff] = hw;

            if (((i + 2) & 7) == 0) {
                __threadfence();                 // drain + make ring stores agent-visible
                __syncthreads();
                if (tid == 0)
                    __hip_atomic_store(&flags[p], (i + 2) >> 3,
                                       __ATOMIC_RELEASE, __HIP_MEMORY_SCOPE_AGENT);
            } else {
                __syncthreads();
            }
        }
        return;   // A blocks write no output
    }

    // ================= B: layer 1 consumer + head =================
    s16x8 wi1f[4][4], wh1f[4][4];
    #pragma unroll
    for (int c = 0; c < 4; ++c) {
        #pragma unroll
        for (int tile = 0; tile < 4; ++tile) {
            const int g  = tile * 128 + w * 16 + n;
            const int k0 = c * 32 + q * 8;
            const float* p1 = Wih1 + g * HDIM + k0;
            const float* p2 = Whh1 + g * HDIM + k0;
            s16x8 a, b;
            #pragma unroll
            for (int j = 0; j < 8; ++j) { a[j] = (short)f2bf(p1[j]); b[j] = (short)f2bf(p2[j]); }
            wi1f[c][tile] = a; wh1f[c][tile] = b;
        }
    }
    uint32_t b1p[8];
    #pragma unroll
    for (int i = 0; i < 8; ++i) {
        const int tr0 = 2 * i;
        const int tile = tr0 >> 2, r0 = tr0 & 3;
        const int g0 = tile * 128 + u0 + r0;
        const int g1 = g0 + 1;
        b1p[i] = ((uint32_t)f2bf(bih1[g1] + bhh1[g1]) << 16) | f2bf(bih1[g0] + bhh1[g0]);
    }
    // zero h1[-1] (read slot for k=0 is h1f[1])
    for (int s2 = tid; s2 < 1024; s2 += 512) ((uint32_t*)h1f[1])[s2] = 0u;
    float c1v[4] = {0.f, 0.f, 0.f, 0.f};

#define WAITCHUNK(C) do {                                                     \
    if (tid == 0) {                                                           \
        while (__hip_atomic_load(&flags[p], __ATOMIC_ACQUIRE,                 \
                                 __HIP_MEMORY_SCOPE_AGENT) < (C))             \
            __builtin_amdgcn_s_sleep(8);                                      \
    }                                                                         \
    __syncthreads();                                                          \
    __threadfence();  /* acquire: invalidate stale cached ring lines */       \
} while (0)

#define LOADCUR(DST, T) do {                                                  \
    _Pragma("unroll")                                                         \
    for (int c = 0; c < 4; ++c)                                               \
        (DST)[c] = *(const s16x8*)&ringp[(size_t)(T) * 2048 + (c * 64 + l) * 8]; \
} while (0)

#define BSTEP(K, CUR, NXT, DO_PF) do {                                        \
    const short* R1_ = h1f[((K) + 1) & 1];                                    \
    short*       W1_ = h1f[(K) & 1];                                          \
    s16x8 hb1_[4];                                                            \
    _Pragma("unroll")                                                         \
    for (int c = 0; c < 4; ++c) hb1_[c] = *(const s16x8*)&R1_[(c * 64 + l) * 8]; \
    f32x4 a_[4];                                                              \
    _Pragma("unroll")                                                         \
    for (int tile = 0; tile < 4; ++tile) {                                    \
        _Pragma("unroll")                                                     \
        for (int r = 0; r < 4; ++r) a_[tile][r] = UNPK(b1p, tile * 4 + r);    \
    }                                                                         \
    _Pragma("unroll")                                                         \
    for (int c = 0; c < 4; ++c) {                                             \
        _Pragma("unroll")                                                     \
        for (int tile = 0; tile < 4; ++tile)                                  \
            a_[tile] = MFMA16(wi1f[c][tile], (CUR)[c], a_[tile]);             \
    }                                                                         \
    if (DO_PF) { LOADCUR(NXT, (K) + 1); }                                     \
    _Pragma("unroll")                                                         \
    for (int c = 0; c < 4; ++c) {                                             \
        _Pragma("unroll")                                                     \
        for (int tile = 0; tile < 4; ++tile)                                  \
            a_[tile] = MFMA16(wh1f[c][tile], hb1_[c], a_[tile]);              \
    }                                                                         \
    s16x4 hw_;                                                                \
    _Pragma("unroll")                                                         \
    for (int r = 0; r < 4; ++r) {                                             \
        const float ig = sigmoidf_(a_[0][r]);                                 \
        const float fg = sigmoidf_(a_[1][r]);                                 \
        const float gg = tanhf_(a_[2][r]);                                    \
        const float og = sigmoidf_(a_[3][r]);                                 \
        const float cc = fmaf(fg, c1v[r], ig * gg);                           \
        c1v[r] = cc;                                                          \
        hw_[r] = (short)f2bf(og * tanhf_(cc));                                \
    }                                                                         \
    *(s16x4*)&W1_[fragoff] = hw_;                                             \
    __syncthreads();                                                          \
} while (0)

    s16x8 curA[4], curB[4];

    #pragma unroll 1
    for (int c64 = 0; c64 < 63; ++c64) {
        WAITCHUNK(c64 + 1);
        const int kb = 8 * c64;
        LOADCUR(curA, kb);
        BSTEP(kb + 0, curA, curB, true);
        BSTEP(kb + 1, curB, curA, true);
        BSTEP(kb + 2, curA, curB, true);
        BSTEP(kb + 3, curB, curA, true);
        BSTEP(kb + 4, curA, curB, true);
        BSTEP(kb + 5, curB, curA, true);
        BSTEP(kb + 6, curA, curB, true);
        BSTEP(kb + 7, curB, curA, false);
    }
    // final chunk: k = 504..510, then epilogue k = 511
    WAITCHUNK(64);
    LOADCUR(curA, 504);
    BSTEP(504, curA, curB, true);
    BSTEP(505, curB, curA, true);
    BSTEP(506, curA, curB, true);
    BSTEP(507, curB, curA, true);
    BSTEP(508, curA, curB, true);
    BSTEP(509, curB, curA, true);
    BSTEP(510, curA, curB, true);        // prefetches curB = h0[511]

    // epilogue t=511: gates1 only; final h1 -> headH (f32)
    {
        const short* R1 = h1f[0];        // h1[510]
        s16x8 hb1_[4];
        #pragma unroll
        for (int c = 0; c < 4; ++c) hb1_[c] = *(const s16x8*)&R1[(c * 64 + l) * 8];
        f32x4 a_[4];
        #pragma unroll
        for (int tile = 0; tile < 4; ++tile) {
            #pragma unroll
            for (int r = 0; r < 4; ++r) a_[tile][r] = UNPK(b1p, tile * 4 + r);
        }
        #pragma unroll
        for (int c = 0; c < 4; ++c) {
            #pragma unroll
            for (int tile = 0; tile < 4; ++tile) {
                a_[tile] = MFMA16(wi1f[c][tile], curB[c], a_[tile]);
                a_[tile] = MFMA16(wh1f[c][tile], hb1_[c], a_[tile]);
            }
        }
        f32x4 hv;
        #pragma unroll
        for (int r = 0; r < 4; ++r) {
            const float ig = sigmoidf_(a_[0][r]);
            const float fg = sigmoidf_(a_[1][r]);
            const float gg = tanhf_(a_[2][r]);
            const float og = sigmoidf_(a_[3][r]);
            const float cc = fmaf(fg, c1v[r], ig * gg);
            hv[r] = og * tanhf_(cc);
        }
        *(f32x4*)&headH[n * HDIM + u0] = hv;
    }
    __syncthreads();

    #pragma unroll
    for (int rep = 0; rep < 2; ++rep) {
        const int idx = tid + rep * 512;     // 1024 = 16 batch * 64 hidden
        const int nn = idx >> 6, j = idx & 63;
        float s = b1[j];
        const float* wrow = W1 + j * HDIM;
        const float* hrow = headH + nn * HDIM;
        #pragma unroll
        for (int k = 0; k < HDIM; k += 4) {
            const f32x4 hv = *(const f32x4*)&hrow[k];
            const f32x4 wv = *(const f32x4*)&wrow[k];
            s += hv[0]*wv[0] + hv[1]*wv[1] + hv[2]*wv[2] + hv[3]*wv[3];
        }
        headL[nn * 64 + j] = fmaxf(s, 0.0f);
    }
    __syncthreads();

    if (tid < 128) {
        const int nn = tid >> 3, cls = tid & 7;
        float s = b2[cls];
        const float* wrow = W2 + cls * 64;
        const float* hrow = headL + nn * 64;
        #pragma unroll
        for (int k = 0; k < 64; k += 4) {
            const f32x4 hv = *(const f32x4*)&hrow[k];
            const f32x4 wv = *(const f32x4*)&wrow[k];
            s += hv[0]*wv[0] + hv[1]*wv[1] + hv[2]*wv[2] + hv[3]*wv[3];
        }
        out[(size_t)(b0 + nn) * 8 + cls] = s;
    }
#undef WAITCHUNK
#undef LOADCUR
#undef BSTEP
}

// ============================================================================
// Fallback (round-6 kernel, 954 us): used when ws_size is too small.
// ============================================================================
__global__ __launch_bounds__(512, 2) void lstm_fused_kernel(
    const float* __restrict__ x,
    const float* __restrict__ Wih0,
    const float* __restrict__ Whh0,
    const float* __restrict__ bih0,
    const float* __restrict__ bhh0,
    const float* __restrict__ Wih1,
    const float* __restrict__ Whh1,
    const float* __restrict__ bih1,
    const float* __restrict__ bhh1,
    const float* __restrict__ W1,
    const float* __restrict__ b1,
    const float* __restrict__ W2,
    const float* __restrict__ b2,
    float* __restrict__ out)
{
    __shared__ __align__(16) short wh1lds[65536];
    __shared__ __align__(16) short h0f0[2048], h0f1[2048];
    __shared__ __align__(16) short h1f0[2048], h1f1[2048];
    __shared__ __align__(16) float b1lds[4][8][16];

    const int tid = threadIdx.x;
    const int w   = tid >> 6;
    const int wl  = w & 3;
    const bool isL0 = (w < 4);
    const int l = tid & 63;
    const int n = l & 15;
    const int q = l >> 4;
    const int b0 = blockIdx.x * BT;
    const float* xrow = x + (size_t)(b0 + n) * TLEN;

    for (int s2 = tid; s2 < 8192; s2 += 512) {
        const int ll = s2 & 63, t2 = (s2 >> 6) & 7, cc = (s2 >> 9) & 3, wv = s2 >> 11;
        const int row = (t2 >> 1) * 128 + 32 * wv + 16 * (t2 & 1) + (ll & 15);
        const int k0  = cc * 32 + (ll >> 4) * 8;
        const float* p = Whh1 + row * HDIM + k0;
        s16x8 a;
        #pragma unroll
        for (int j = 0; j < 8; ++j) a[j] = (short)f2bf(p[j]);
        *(s16x8*)&wh1lds[s2 * 8] = a;
    }
    {
        const int idx = tid;
        const int wv = idx >> 7, t2 = (idx >> 4) & 7, j = idx & 15;
        const int row = (t2 >> 1) * 128 + 32 * wv + 16 * (t2 & 1) + j;
        b1lds[wv][t2][j] = bih1[row] + bhh1[row];
    }
    for (int s2 = tid; s2 < 1024; s2 += 512) ((uint32_t*)h1f1)[s2] = 0u;

    const int ub0 = 32 * wl + 4 * q;
    const int ub1 = ub0 + 16;
    const int fo0 = ((ub0 >> 5) * 64 + n + 16 * ((ub0 >> 3) & 3)) * 8 + (ub0 & 7);
    const int fo1 = ((ub1 >> 5) * 64 + n + 16 * ((ub1 >> 3) & 3)) * 8 + (ub1 & 7);

#define L0ITER(K, R0, W0) do {                                                \
    const int xi_ = (K) + 1;                                                  \
    const float xv_ = xrow[xi_ < TLEN ? xi_ : (TLEN - 1)];                    \
    s16x8 hb_[4];                                                             \
    _Pragma("unroll")                                                         \
    for (int c = 0; c < 4; ++c) hb_[c] = *(const s16x8*)&(R0)[(c * 64 + l) * 8]; \
    f32x4 a_[8];                                                              \
    _Pragma("unroll")                                                         \
    for (int t2 = 0; t2 < 8; ++t2) {                                          \
        _Pragma("unroll")                                                     \
        for (int r = 0; r < 4; ++r)                                           \
            a_[t2][r] = fmaf(bfhi(bwx[t2][r]), xv_, bflo(bwx[t2][r]));        \
    }                                                                         \
    _Pragma("unroll")                                                         \
    for (int c = 0; c < 4; ++c) {                                             \
        _Pragma("unroll")                                                     \
        for (int t2 = 0; t2 < 8; ++t2)                                        \
            a_[t2] = MFMA16(w0f[c][t2], hb_[c], a_[t2]);                      \
    }                                                                         \
    _Pragma("unroll")                                                         \
    for (int h = 0; h < 2; ++h) {                                             \
        s16x4 hw;                                                             \
        _Pragma("unroll")                                                     \
        for (int r = 0; r < 4; ++r) {                                         \
            const float ig = sigmoidf_(a_[0 + h][r]);                         \
            const float fg = sigmoidf_(a_[2 + h][r]);                         \
            const float gg = tanhf_(a_[4 + h][r]);                            \
            const float og = sigmoidf_(a_[6 + h][r]);                         \
            const float cc = fmaf(fg, c0_[h][r], ig * gg);                    \
            c0_[h][r] = cc;                                                   \
            hw[r] = (short)f2bf(og * tanhf_(cc));                             \
        }                                                                     \
        *(s16x4*)&(W0)[h ? fo1 : fo0] = hw;                                   \
    }                                                                         \
    __syncthreads();                                                          \
} while (0)

#define L1ITER(K, R0, R1, W1) do {                                            \
    s16x8 hb0_[4], hb1_[4];                                                   \
    _Pragma("unroll")                                                         \
    for (int c = 0; c < 4; ++c) {                                             \
        hb0_[c] = *(const s16x8*)&(R0)[(c * 64 + l) * 8];                     \
        hb1_[c] = *(const s16x8*)&(R1)[(c * 64 + l) * 8];                     \
    }                                                                         \
    f32x4 a_[8];                                                              \
    _Pragma("unroll")                                                         \
    for (int t2 = 0; t2 < 8; ++t2)                                            \
        a_[t2] = *(const f32x4*)&b1lds[wl][t2][q * 4];                        \
    _Pragma("unroll")                                                         \
    for (int c = 0; c < 4; ++c) {                                             \
        _Pragma("unroll")                                                     \
        for (int t2 = 0; t2 < 8; ++t2)                                        \
            a_[t2] = MFMA16(wi1f[c][t2], hb0_[c], a_[t2]);                    \
    }                                                                         \
    _Pragma("unroll")                                                         \
    for (int c = 0; c < 4; ++c) {                                             \
        s16x8 wt_[8];                                                         \
        _Pragma("unroll")                                                     \
        for (int t2 = 0; t2 < 8; ++t2)                                        \
            wt_[t2] = *(const s16x8*)&wh1lds[(((wl * 4 + c) * 8 + t2) * 64 + l) * 8]; \
        _Pragma("unroll")                                                     \
        for (int t2 = 0; t2 < 8; ++t2)                                        \
            a_[t2] = MFMA16(wt_[t2], hb1_[c], a_[t2]);                        \
    }                                                                         \
    _Pragma("unroll")                                                         \
    for (int h = 0; h < 2; ++h) {                                             \
        s16x4 hw;                                                             \
        _Pragma("unroll")                                                     \
        for (int r = 0; r < 4; ++r) {                                         \
            const float ig = sigmoidf_(a_[0 + h][r]);                         \
            const float fg = sigmoidf_(a_[2 + h][r]);                         \
            const float gg = tanhf_(a_[4 + h][r]);                            \
            const float og = sigmoidf_(a_[6 + h][r]);                         \
            const float cc = fmaf(fg, c1_[h][r], ig * gg);                    \
            c1_[h][r] = cc;                                                   \
            hw[r] = (short)f2bf(og * tanhf_(cc));                             \
        }                                                                     \
        *(s16x4*)&(W1)[h ? fo1 : fo0] = hw;                                   \
    }                                                                         \
    __syncthreads();                                                          \
} while (0)

    if (isL0) {
        s16x8 w0f[4][8];
        #pragma unroll
        for (int c = 0; c < 4; ++c) {
            #pragma unroll
            for (int t2 = 0; t2 < 8; ++t2) {
                const int row = (t2 >> 1) * 128 + 32 * wl + 16 * (t2 & 1) + n;
                const int k0 = c * 32 + q * 8;
                const float* p = Whh0 + row * HDIM + k0;
                s16x8 a;
                #pragma unroll
                for (int j = 0; j < 8; ++j) a[j] = (short)f2bf(p[j]);
                w0f[c][t2] = a;
            }
        }
        u32x4 bwx[8];
        #pragma unroll
        for (int t2 = 0; t2 < 8; ++t2) {
            #pragma unroll
            for (int r = 0; r < 4; ++r) {
                const int row = (t2 >> 1) * 128 + 32 * wl + 16 * (t2 & 1) + 4 * q + r;
                bwx[t2][r] = ((uint32_t)f2bf(Wih0[row]) << 16) | f2bf(bih0[row] + bhh0[row]);
            }
        }
        float c0_[2][4] = {{0.f,0.f,0.f,0.f},{0.f,0.f,0.f,0.f}};
        {
            const float x0 = xrow[0];
            #pragma unroll
            for (int h = 0; h < 2; ++h) {
                s16x4 hw;
                #pragma unroll
                for (int r = 0; r < 4; ++r) {
                    const float pi = fmaf(bfhi(bwx[0 + h][r]), x0, bflo(bwx[0 + h][r]));
                    const float pg = fmaf(bfhi(bwx[4 + h][r]), x0, bflo(bwx[4 + h][r]));
                    const float po = fmaf(bfhi(bwx[6 + h][r]), x0, bflo(bwx[6 + h][r]));
                    const float ig = sigmoidf_(pi);
                    const float gg = tanhf_(pg);
                    const float og = sigmoidf_(po);
                    const float cc = ig * gg;
                    c0_[h][r] = cc;
                    hw[r] = (short)f2bf(og * tanhf_(cc));
                }
                *(s16x4*)&h0f0[h ? fo1 : fo0] = hw;
            }
        }
        __syncthreads();
        #pragma unroll 1
        for (int k = 0; k < TLEN; k += 2) {
            L0ITER(k,     h0f0, h0f1);
            L0ITER(k + 1, h0f1, h0f0);
        }
    } else {
        s16x8 wi1f[4][8];
        #pragma unroll
        for (int c = 0; c < 4; ++c) {
            #pragma unroll
            for (int t2 = 0; t2 < 8; ++t2) {
                const int row = (t2 >> 1) * 128 + 32 * wl + 16 * (t2 & 1) + n;
                const int k0 = c * 32 + q * 8;
                const float* p = Wih1 + row * HDIM + k0;
                s16x8 a;
                #pragma unroll
                for (int j = 0; j < 8; ++j) a[j] = (short)f2bf(p[j]);
                wi1f[c][t2] = a;
            }
        }
        float c1_[2][4] = {{0.f,0.f,0.f,0.f},{0.f,0.f,0.f,0.f}};
        __syncthreads();
        #pragma unroll 1
        for (int k = 0; k < TLEN; k += 2) {
            L1ITER(k,     h0f0, h1f1, h1f0);
            L1ITER(k + 1, h0f1, h1f0, h1f1);
        }
        {
            const short* R0 = h0f0;
            const short* R1 = h1f1;
            // NOTE: loop ran to TLEN (512) producing one extra h0/h1 past 511;
            // h1[511] itself is what we need: it was produced at k=511 into h1f1.
            (void)R0; (void)R1;
        }
    }

    __syncthreads();

    float* headH = (float*)wh1lds;
    float* headL = headH + 16 * HDIM;
    if (!isL0) {
        #pragma unroll
        for (int h = 0; h < 2; ++h) {
            const s16x4 hv = *(const s16x4*)&h1f1[h ? fo1 : fo0];
            f32x4 hf;
            #pragma unroll
            for (int r = 0; r < 4; ++r) hf[r] = bf2f(hv[r]);
            *(f32x4*)&headH[n * HDIM + (h ? ub1 : ub0)] = hf;
        }
    }
    __syncthreads();

    #pragma unroll
    for (int rep = 0; rep < 2; ++rep) {
        const int idx = tid + rep * 512;
        const int nn = idx >> 6, j = idx & 63;
        float s = b1[j];
        const float* wrow = W1 + j * HDIM;
        const float* hrow = headH + nn * HDIM;
        #pragma unroll
        for (int k = 0; k < HDIM; k += 4) {
            const f32x4 hv = *(const f32x4*)&hrow[k];
            const f32x4 wv = *(const f32x4*)&wrow[k];
            s += hv[0]*wv[0] + hv[1]*wv[1] + hv[2]*wv[2] + hv[3]*wv[3];
        }
        headL[nn * 64 + j] = fmaxf(s, 0.0f);
    }
    __syncthreads();

    if (tid < 128) {
        const int nn = tid >> 3, cls = tid & 7;
        float s = b2[cls];
        const float* wrow = W2 + cls * 64;
        const float* hrow = headL + nn * 64;
        #pragma unroll
        for (int k = 0; k < 64; k += 4) {
            const f32x4 hv = *(const f32x4*)&hrow[k];
            const f32x4 wv = *(const f32x4*)&wrow[k];
            s += hv[0]*wv[0] + hv[1]*wv[1] + hv[2]*wv[2] + hv[3]*wv[3];
        }
        out[(size_t)(b0 + nn) * 8 + cls] = s;
    }
#undef L0ITER
#undef L1ITER
}

extern "C" void kernel_launch(void* const* d_in, const int* in_sizes, int n_in,
                              void* d_out, int out_size, void* d_ws, size_t ws_size,
                              hipStream_t stream) {
    const float* x    = (const float*)d_in[0];
    const float* Wih0 = (const float*)d_in[1];
    const float* Whh0 = (const float*)d_in[2];
    const float* bih0 = (const float*)d_in[3];
    const float* bhh0 = (const float*)d_in[4];
    const float* Wih1 = (const float*)d_in[5];
    const float* Whh1 = (const float*)d_in[6];
    const float* bih1 = (const float*)d_in[7];
    const float* bhh1 = (const float*)d_in[8];
    const float* W1   = (const float*)d_in[9];
    const float* b1   = (const float*)d_in[10];
    const float* W2   = (const float*)d_in[11];
    const float* b2   = (const float*)d_in[12];
    float* outp = (float*)d_out;

    const size_t ring_bytes = (size_t)128 * TLEN * 2048 * sizeof(short); // 256 MB
    const size_t need = 4096 + ring_bytes;

    if (ws_size >= need) {
        int*   flags = (int*)d_ws;
        short* ring  = (short*)((char*)d_ws + 4096);
        hipMemsetAsync(d_ws, 0, 4096, stream);   // zero flags every launch
        lstm_pipe_kernel<<<256, 512, 0, stream>>>(
            x, Wih0, Whh0, bih0, bhh0, Wih1, Whh1, bih1, bhh1,
            W1, b1, W2, b2, ring, flags, outp);
    } else {
        lstm_fused_kernel<<<128, 512, 0, stream>>>(
            x, Wih0, Whh0, bih0, bhh0, Wih1, Whh1, bih1, bhh1,
            W1, b1, W2, b2, outp);
    }
}